// Round 4
// baseline (17459.595 us; speedup 1.0000x reference)
//
#include <hip/hip_runtime.h>

typedef short short8 __attribute__((ext_vector_type(8)));
typedef float f32x4 __attribute__((ext_vector_type(4)));
typedef unsigned short u16;

#define Bz   32
#define Sz   512
#define DIN  512
#define DH   1024
#define DOUT 512
#define KTOT 1536
#define NWG  256
#define NTH  256
#define TPW  12      // k-tiles (of 32) per wave; 4 waves x 12 = 48 = KTOT/32
#define PADB (76 * 1024)   // dynamic-LDS pad -> 1 wg/CU (runtime-visible, no DCE)

// ---- bf16 split helpers (RNE) ----
__device__ __forceinline__ u16 bf_rne(float f) {
  unsigned b = __float_as_uint(f);
  return (u16)((b + 0x7fffu + ((b >> 16) & 1u)) >> 16);
}
__device__ __forceinline__ float bf_f(u16 h) { return __uint_as_float(((unsigned)h) << 16); }
__device__ __forceinline__ void bf_split(float f, u16& hi, u16& lo) {
  hi = bf_rne(f);
  lo = bf_rne(f - bf_f(hi));
}

__device__ __forceinline__ float sigm(float v) { return 1.0f / (1.0f + __expf(-v)); }

__device__ __forceinline__ f32x4 mfma16(short8 a, short8 b, f32x4 c) {
  return __builtin_amdgcn_mfma_f32_16x16x32_bf16(a, b, c, 0, 0, 0);
}

// ---- monotone grid barrier (needs all wgs co-resident) ----
__device__ __forceinline__ void grid_bar(unsigned* bar, unsigned target) {
  __syncthreads();
  if (threadIdx.x == 0) {
    __hip_atomic_fetch_add(bar, 1u, __ATOMIC_ACQ_REL, __HIP_MEMORY_SCOPE_AGENT);
    while (__hip_atomic_load(bar, __ATOMIC_ACQUIRE, __HIP_MEMORY_SCOPE_AGENT) < target) {
      __builtin_amdgcn_s_sleep(1);
    }
  }
  __syncthreads();
}

// ---- x fp32 -> (hi, lo) bf16 split, layout-preserving [B][S][DIN] ----
__global__ __launch_bounds__(256)
void xsplit(const float* __restrict__ x, u16* __restrict__ xhi, u16* __restrict__ xlo) {
  const int i = (blockIdx.x * 256 + threadIdx.x) * 4;   // grid sized exactly
  const float4 v = *(const float4*)(x + i);
  u16 h0, l0, h1, l1, h2, l2, h3, l3;
  bf_split(v.x, h0, l0); bf_split(v.y, h1, l1);
  bf_split(v.z, h2, l2); bf_split(v.w, h3, l3);
  ushort4 hv = {h0, h1, h2, h3}, lv = {l0, l1, l2, l3};
  *(ushort4*)(xhi + i) = hv;
  *(ushort4*)(xlo + i) = lv;
}

// ---- persistent cooperative LSTM recurrence ----
// wg owns 16 gate-interleaved columns: c = 4*j + g, hidden col = wg*4 + j.
// Wave wid owns k-tiles [wid*12, wid*12+12) as register B-frags (hi/lo bf16).
// A-frags load straight from global (xhi/xlo for k<512, h ping-pong bf16 pair
// for k>=512). Cross-wave K-reduction via an 8 KB LDS dump.
__global__ __launch_bounds__(NTH, 1)
void lstm_rec(const u16* __restrict__ xhi, const u16* __restrict__ xlo,
              const float* __restrict__ Wf, const float* __restrict__ bfv,
              const float* __restrict__ Wi, const float* __restrict__ biv,
              const float* __restrict__ Wg, const float* __restrict__ bgv,
              const float* __restrict__ Wo, const float* __restrict__ bov,
              u16* __restrict__ hhi, u16* __restrict__ hlo,   // [2][Bz][DH] each
              float* __restrict__ hs,                         // [Bz][Sz][DH]
              unsigned* __restrict__ bar)
{
  __shared__ __align__(16) float pdump[4][2][64][4];  // [wave][mtile][lane][reg] 8 KB
  __shared__ float csh[Bz][4];                        // c-state, persistent
  __shared__ float bsh[16];
  extern __shared__ char dynpad[];                    // launch-time pad (occupancy pin)

  const int tid  = threadIdx.x;
  const int wg   = blockIdx.x;
  const int wid  = tid >> 6;
  const int lane = tid & 63;
  const int c    = lane & 15;       // gate-col: g = c&3, j = c>>2
  const int q    = lane >> 4;       // k-subgroup (8 k each)
  const int g    = c & 3;
  const int jl   = c >> 2;
  const int col  = wg * 4 + jl;

  // ---- one-time: W slice -> register B-frags, hi/lo split ----
  const float* Wsrc = (g == 0) ? Wf : (g == 1) ? Wi : (g == 2) ? Wg : Wo;
  short8 Bhi[TPW], Blo[TPW];
  #pragma unroll
  for (int tt = 0; tt < TPW; ++tt) {
    const int k0 = (wid * TPW + tt) * 32 + q * 8;
    short8 bh, bl;
    #pragma unroll
    for (int i = 0; i < 8; ++i) {
      u16 h, l;
      bf_split(Wsrc[(k0 + i) * DH + col], h, l);
      bh[i] = (short)h; bl[i] = (short)l;
    }
    Bhi[tt] = bh; Blo[tt] = bl;
  }
  if (tid < 16) {
    const int g2 = tid & 3;
    const float* bsrc = (g2 == 0) ? bfv : (g2 == 1) ? biv : (g2 == 2) ? bgv : bov;
    bsh[tid] = bsrc[wg * 4 + (tid >> 2)];
  }
  if (tid < 128) {
    csh[tid & 31][tid >> 5] = 0.0f;
    const int idx = wg * 128 + tid;   // zero h0 (buffer 0): 32768 entries / 256 wgs
    hhi[idx] = 0; hlo[idx] = 0;
  }
  grid_bar(bar, NWG);

  const int bA = lane & 15;           // A-frag row = batch (m=0: bA, m=1: bA+16)

  for (int t = 0; t < Sz; ++t) {
    const u16* __restrict__ hh = hhi + (t & 1) * (Bz * DH);
    const u16* __restrict__ hl = hlo + (t & 1) * (Bz * DH);

    f32x4 a_hh0 = {0.f,0.f,0.f,0.f}, a_hl0 = a_hh0, a_lh0 = a_hh0;
    f32x4 a_hh1 = a_hh0, a_hl1 = a_hh0, a_lh1 = a_hh0;

    #pragma unroll
    for (int tt = 0; tt < TPW; ++tt) {
      const int k = (wid * TPW + tt) * 32 + q * 8;
      short8 Ah0, Al0, Ah1, Al1;
      if (k < DIN) {                   // x part of comb
        Ah0 = *(const short8*)(xhi + ((bA * Sz + t) * DIN + k));
        Ah1 = *(const short8*)(xhi + (((bA + 16) * Sz + t) * DIN + k));
        Al0 = *(const short8*)(xlo + ((bA * Sz + t) * DIN + k));
        Al1 = *(const short8*)(xlo + (((bA + 16) * Sz + t) * DIN + k));
      } else {                         // h part of comb
        const int kh = k - DIN;
        Ah0 = *(const short8*)(hh + bA * DH + kh);
        Ah1 = *(const short8*)(hh + (bA + 16) * DH + kh);
        Al0 = *(const short8*)(hl + bA * DH + kh);
        Al1 = *(const short8*)(hl + (bA + 16) * DH + kh);
      }
      a_hh0 = mfma16(Ah0, Bhi[tt], a_hh0);   // 3-term bf16x3 product, 6 indep chains
      a_hl0 = mfma16(Ah0, Blo[tt], a_hl0);
      a_lh0 = mfma16(Al0, Bhi[tt], a_lh0);
      a_hh1 = mfma16(Ah1, Bhi[tt], a_hh1);
      a_hl1 = mfma16(Ah1, Blo[tt], a_hl1);
      a_lh1 = mfma16(Al1, Bhi[tt], a_lh1);
    }
    const f32x4 acc0 = a_hh0 + a_hl0 + a_lh0;
    const f32x4 acc1 = a_hh1 + a_hl1 + a_lh1;
    *(f32x4*)&pdump[wid][0][lane][0] = acc0;
    *(f32x4*)&pdump[wid][1][lane][0] = acc1;
    __syncthreads();

    if (tid < 128) {                   // pointwise: thread -> (b, j)
      const int b = tid & 31, j = tid >> 5;
      const int m = b >> 4, r = b & 15, rg = r & 3;
      float G[4];
      #pragma unroll
      for (int g2 = 0; g2 < 4; ++g2) {
        const int ln = (r >> 2) * 16 + (j * 4 + g2);   // D: col=lane&15, row=(lane>>4)*4+reg
        G[g2] = bsh[j * 4 + g2] + pdump[0][m][ln][rg] + pdump[1][m][ln][rg]
              + pdump[2][m][ln][rg] + pdump[3][m][ln][rg];
      }
      const float fv = sigm(G[0]);
      const float iv = sigm(G[1]);
      const float gv = tanhf(G[2]);
      const float ov = sigm(G[3]);
      const float cn = fv * csh[b][j] + iv * gv;
      csh[b][j] = cn;
      const float hv = ov * tanhf(cn);
      u16 hx, lx; bf_split(hv, hx, lx);
      const int par = ((t + 1) & 1) * (Bz * DH);
      hhi[par + b * DH + wg * 4 + j] = hx;
      hlo[par + b * DH + wg * 4 + j] = lx;
      hs[(b * Sz + t) * DH + wg * 4 + j] = hv;
    }
    grid_bar(bar, (unsigned)(t + 2) * NWG);
  }
}

// ---- final FC: [16384,1024] @ [1024,512] + bias, fp32, 64x64 tile, 4x4 micro ----
__global__ __launch_bounds__(256)
void lstm_fc(const float* __restrict__ hs, const float* __restrict__ Wfc,
             const float* __restrict__ bfc, float* __restrict__ out)
{
  __shared__ __align__(16) float Ash[16][68];
  __shared__ __align__(16) float Bsh[16][68];
  const int tid = threadIdx.x;
  const int mt = (int)(blockIdx.x >> 3) * 64;
  const int nt = (int)(blockIdx.x & 7) * 64;
  const int ty = tid >> 4, tx = tid & 15;
  const int am = tid & 63, ak = (tid >> 6) * 4;
  const int bk = tid >> 4, bn = (tid & 15) * 4;
  float acc[4][4] = {};
  for (int k0 = 0; k0 < DH; k0 += 16) {
    const float4 av = *(const float4*)&hs[(mt + am) * DH + k0 + ak];
    const float4 bv = *(const float4*)&Wfc[(k0 + bk) * DOUT + nt + bn];
    Ash[ak + 0][am] = av.x;
    Ash[ak + 1][am] = av.y;
    Ash[ak + 2][am] = av.z;
    Ash[ak + 3][am] = av.w;
    *(float4*)&Bsh[bk][bn] = bv;
    __syncthreads();
    #pragma unroll
    for (int kk = 0; kk < 16; ++kk) {
      const float4 a = *(const float4*)&Ash[kk][ty * 4];
      const float4 b = *(const float4*)&Bsh[kk][tx * 4];
      const float avv[4] = {a.x, a.y, a.z, a.w};
      const float bvv[4] = {b.x, b.y, b.z, b.w};
      #pragma unroll
      for (int i = 0; i < 4; ++i)
        #pragma unroll
        for (int j = 0; j < 4; ++j)
          acc[i][j] = fmaf(avv[i], bvv[j], acc[i][j]);
    }
    __syncthreads();
  }
  const float4 bb = *(const float4*)&bfc[nt + tx * 4];
  const float bias[4] = {bb.x, bb.y, bb.z, bb.w};
  #pragma unroll
  for (int i = 0; i < 4; ++i) {
    float4 o;
    o.x = acc[i][0] + bias[0];
    o.y = acc[i][1] + bias[1];
    o.z = acc[i][2] + bias[2];
    o.w = acc[i][3] + bias[3];
    *(float4*)&out[(mt + ty * 4 + i) * DOUT + nt + tx * 4] = o;
  }
}

extern "C" void kernel_launch(void* const* d_in, const int* in_sizes, int n_in,
                              void* d_out, int out_size, void* d_ws, size_t ws_size,
                              hipStream_t stream) {
  const float* x   = (const float*)d_in[0];
  const float* Wf  = (const float*)d_in[1];
  const float* bf  = (const float*)d_in[2];
  const float* Wi  = (const float*)d_in[3];
  const float* bi  = (const float*)d_in[4];
  const float* Wg  = (const float*)d_in[5];
  const float* bg  = (const float*)d_in[6];
  const float* Wo  = (const float*)d_in[7];
  const float* bo  = (const float*)d_in[8];
  const float* Wfc = (const float*)d_in[9];
  const float* bfc = (const float*)d_in[10];
  float* out = (float*)d_out;

  // ws layout (16B-aligned): bar | hhi | hlo | xhi | xlo | hs  (~96.3 MB)
  char* w = (char*)d_ws;
  unsigned* bar = (unsigned*)w;                       size_t off = 1024;
  u16* hhi = (u16*)(w + off);                         off += 2u * Bz * DH * sizeof(u16);
  u16* hlo = (u16*)(w + off);                         off += 2u * Bz * DH * sizeof(u16);
  u16* xhi = (u16*)(w + off);                         off += (size_t)Bz * Sz * DIN * sizeof(u16);
  u16* xlo = (u16*)(w + off);                         off += (size_t)Bz * Sz * DIN * sizeof(u16);
  float* hs = (float*)(w + off);

  hipMemsetAsync(d_ws, 0, 1024, stream);              // zero barrier counter

  const int xN = Bz * Sz * DIN;                       // 8,388,608 (exactly 8192*256*4)
  hipLaunchKernelGGL(xsplit, dim3(xN / (256 * 4)), dim3(256), 0, stream, x, xhi, xlo);

  void* args[14] = {&xhi, &xlo, &Wf, &bf, &Wi, &bi, &Wg, &bg, &Wo, &bo,
                    &hhi, &hlo, &hs, &bar};
  // Fast path: cooperative launch with a 76 KB dynamic-LDS pad (pins 1 wg/CU).
  hipError_t ce = hipLaunchCooperativeKernel((void*)lstm_rec, dim3(NWG), dim3(NTH),
                                             args, PADB, stream);
  if (ce != hipSuccess) {
    // Fallback: plain launch, no pad (256 wgs <= resident capacity -> co-resident).
    hipLaunchKernelGGL(lstm_rec, dim3(NWG), dim3(NTH), 0, stream,
                       xhi, xlo, Wf, bf, Wi, bi, Wg, bg, Wo, bo, hhi, hlo, hs, bar);
  }

  hipLaunchKernelGGL(lstm_fc, dim3((Bz * Sz / 64) * (DOUT / 64)), dim3(256), 0, stream,
                     hs, Wfc, bfc, out);
}

// Round 7
// 11093.766 us; speedup vs baseline: 1.5738x; 1.5738x over previous
//
#include <hip/hip_runtime.h>

typedef short short8 __attribute__((ext_vector_type(8)));
typedef float f32x4 __attribute__((ext_vector_type(4)));
typedef unsigned short u16;

#define Bz   32
#define Sz   512
#define DIN  512
#define DH   1024
#define DOUT 512
#define KTOT 1536
#define NWG  256
#define NTH  256
#define TPW  12      // k-tiles (of 32) per wave; 4 waves x 12 = 48 = KTOT/32

// ---- bf16 split helpers (RNE) ----
__device__ __forceinline__ u16 bf_rne(float f) {
  unsigned b = __float_as_uint(f);
  return (u16)((b + 0x7fffu + ((b >> 16) & 1u)) >> 16);
}
__device__ __forceinline__ float bf_f(u16 h) { return __uint_as_float(((unsigned)h) << 16); }
__device__ __forceinline__ void bf_split(float f, u16& hi, u16& lo) {
  hi = bf_rne(f);
  lo = bf_rne(f - bf_f(hi));
}

__device__ __forceinline__ float sigm(float v) { return 1.0f / (1.0f + __expf(-v)); }

__device__ __forceinline__ f32x4 mfma16(short8 a, short8 b, f32x4 c) {
  return __builtin_amdgcn_mfma_f32_16x16x32_bf16(a, b, c, 0, 0, 0);
}

// ---- distributed flag barrier ----
// Per-wg 128B-padded arrive flags (release-stored round number); wg0 polls all
// in parallel, then release-stores the round to *rel; others spin on that one
// read-shared line. Spins use RELAXED loads (no per-poll buffer_inv) + a single
// agent ACQUIRE fence once the value is seen — fence-based sync keeps the
// happens-before chain (wbl2 on release side pushes h-data to L3 first).
__device__ __forceinline__ void grid_bar(unsigned* __restrict__ arrive,
                                         unsigned* __restrict__ rel,
                                         int wg, int tid, unsigned round) {
  __syncthreads();
  if (wg == 0) {
    if (tid > 0) {   // tid 1..255 polls wg tid's flag (reads, distinct lines)
      while (__hip_atomic_load(&arrive[tid * 32], __ATOMIC_RELAXED,
                               __HIP_MEMORY_SCOPE_AGENT) < round)
        __builtin_amdgcn_s_sleep(1);
    }
    __builtin_amdgcn_fence(__ATOMIC_ACQUIRE, "agent");   // one L2-inv, not per poll
    __syncthreads();
    if (tid == 0)
      __hip_atomic_store(rel, round, __ATOMIC_RELEASE, __HIP_MEMORY_SCOPE_AGENT);
  } else {
    if (tid == 0) {
      __hip_atomic_store(&arrive[wg * 32], round, __ATOMIC_RELEASE,
                         __HIP_MEMORY_SCOPE_AGENT);
      while (__hip_atomic_load(rel, __ATOMIC_RELAXED,
                               __HIP_MEMORY_SCOPE_AGENT) < round)
        __builtin_amdgcn_s_sleep(1);
      __builtin_amdgcn_fence(__ATOMIC_ACQUIRE, "agent");
    }
    __syncthreads();
  }
}

// ---- x fp32 -> (hi, lo) bf16 split, layout-preserving [B][S][DIN] ----
__global__ __launch_bounds__(256)
void xsplit(const float* __restrict__ x, u16* __restrict__ xhi, u16* __restrict__ xlo) {
  const int i = (blockIdx.x * 256 + threadIdx.x) * 4;   // grid sized exactly
  const float4 v = *(const float4*)(x + i);
  u16 h0, l0, h1, l1, h2, l2, h3, l3;
  bf_split(v.x, h0, l0); bf_split(v.y, h1, l1);
  bf_split(v.z, h2, l2); bf_split(v.w, h3, l3);
  ushort4 hv = {h0, h1, h2, h3}, lv = {l0, l1, l2, l3};
  *(ushort4*)(xhi + i) = hv;
  *(ushort4*)(xlo + i) = lv;
}

// ---- persistent LSTM recurrence (plain launch; 256 wgs co-resident, R4-verified) ----
// wg owns 16 gate-interleaved columns: c = 4*j + g, hidden col = wg*4 + j.
// Wave wid owns k-tiles [wid*12, wid*12+12) as register B-frags (hi/lo bf16).
// A-frags load straight from global. Cross-wave K-reduction via 8 KB LDS dump.
__global__ __launch_bounds__(NTH, 1)
void lstm_rec(const u16* __restrict__ xhi, const u16* __restrict__ xlo,
              const float* __restrict__ Wf, const float* __restrict__ bfv,
              const float* __restrict__ Wi, const float* __restrict__ biv,
              const float* __restrict__ Wg, const float* __restrict__ bgv,
              const float* __restrict__ Wo, const float* __restrict__ bov,
              u16* __restrict__ hhi, u16* __restrict__ hlo,   // [2][Bz][DH] each
              float* __restrict__ hs,                         // [Bz][Sz][DH]
              unsigned* __restrict__ arrive, unsigned* __restrict__ rel)
{
  __shared__ __align__(16) float pdump[4][2][64][4];  // [wave][mtile][lane][reg] 8 KB
  __shared__ float csh[Bz][4];                        // c-state, persistent
  __shared__ float bsh[16];

  const int tid  = threadIdx.x;
  const int wg   = blockIdx.x;
  const int wid  = tid >> 6;
  const int lane = tid & 63;
  const int c    = lane & 15;       // gate-col: g = c&3, j = c>>2
  const int q    = lane >> 4;       // k-subgroup (8 k each)
  const int g    = c & 3;
  const int jl   = c >> 2;
  const int col  = wg * 4 + jl;

  // ---- one-time: W slice -> register B-frags, hi/lo split ----
  const float* Wsrc = (g == 0) ? Wf : (g == 1) ? Wi : (g == 2) ? Wg : Wo;
  short8 Bhi[TPW], Blo[TPW];
  #pragma unroll
  for (int tt = 0; tt < TPW; ++tt) {
    const int k0 = (wid * TPW + tt) * 32 + q * 8;
    short8 bh, bl;
    #pragma unroll
    for (int i = 0; i < 8; ++i) {
      u16 h, l;
      bf_split(Wsrc[(k0 + i) * DH + col], h, l);
      bh[i] = (short)h; bl[i] = (short)l;
    }
    Bhi[tt] = bh; Blo[tt] = bl;
  }
  if (tid < 16) {
    const int g2 = tid & 3;
    const float* bsrc = (g2 == 0) ? bfv : (g2 == 1) ? biv : (g2 == 2) ? bgv : bov;
    bsh[tid] = bsrc[wg * 4 + (tid >> 2)];
  }
  if (tid < 128) {
    csh[tid & 31][tid >> 5] = 0.0f;
    const int idx = wg * 128 + tid;   // zero h0 (buffer 0): 32768 entries / 256 wgs
    hhi[idx] = 0; hlo[idx] = 0;
  }
  grid_bar(arrive, rel, wg, tid, 1u);

  const int bA = lane & 15;           // A-frag row = batch (m=0: bA, m=1: bA+16)

  for (int t = 0; t < Sz; ++t) {
    const u16* __restrict__ hh = hhi + (t & 1) * (Bz * DH);
    const u16* __restrict__ hl = hlo + (t & 1) * (Bz * DH);

    f32x4 a_hh0 = {0.f,0.f,0.f,0.f}, a_hl0 = a_hh0, a_lh0 = a_hh0;
    f32x4 a_hh1 = a_hh0, a_hl1 = a_hh0, a_lh1 = a_hh0;

    #pragma unroll
    for (int tt = 0; tt < TPW; ++tt) {
      const int k = (wid * TPW + tt) * 32 + q * 8;
      short8 Ah0, Al0, Ah1, Al1;
      if (k < DIN) {                   // x part of comb
        Ah0 = *(const short8*)(xhi + ((bA * Sz + t) * DIN + k));
        Ah1 = *(const short8*)(xhi + (((bA + 16) * Sz + t) * DIN + k));
        Al0 = *(const short8*)(xlo + ((bA * Sz + t) * DIN + k));
        Al1 = *(const short8*)(xlo + (((bA + 16) * Sz + t) * DIN + k));
      } else {                         // h part of comb
        const int kh = k - DIN;
        Ah0 = *(const short8*)(hh + bA * DH + kh);
        Ah1 = *(const short8*)(hh + (bA + 16) * DH + kh);
        Al0 = *(const short8*)(hl + bA * DH + kh);
        Al1 = *(const short8*)(hl + (bA + 16) * DH + kh);
      }
      a_hh0 = mfma16(Ah0, Bhi[tt], a_hh0);   // 3-term bf16x3 product, 6 indep chains
      a_hl0 = mfma16(Ah0, Blo[tt], a_hl0);
      a_lh0 = mfma16(Al0, Bhi[tt], a_lh0);
      a_hh1 = mfma16(Ah1, Bhi[tt], a_hh1);
      a_hl1 = mfma16(Ah1, Blo[tt], a_hl1);
      a_lh1 = mfma16(Al1, Bhi[tt], a_lh1);
    }
    const f32x4 acc0 = a_hh0 + a_hl0 + a_lh0;
    const f32x4 acc1 = a_hh1 + a_hl1 + a_lh1;
    *(f32x4*)&pdump[wid][0][lane][0] = acc0;
    *(f32x4*)&pdump[wid][1][lane][0] = acc1;
    __syncthreads();

    if (tid < 128) {                   // pointwise: thread -> (b, j)
      const int b = tid & 31, j = tid >> 5;
      const int m = b >> 4, r = b & 15, rg = r & 3;
      float G[4];
      #pragma unroll
      for (int g2 = 0; g2 < 4; ++g2) {
        const int ln = (r >> 2) * 16 + (j * 4 + g2);   // D: col=lane&15, row=(lane>>4)*4+reg
        G[g2] = bsh[j * 4 + g2] + pdump[0][m][ln][rg] + pdump[1][m][ln][rg]
              + pdump[2][m][ln][rg] + pdump[3][m][ln][rg];
      }
      const float fv = sigm(G[0]);
      const float iv = sigm(G[1]);
      const float gv = tanhf(G[2]);
      const float ov = sigm(G[3]);
      const float cn = fv * csh[b][j] + iv * gv;
      csh[b][j] = cn;
      const float hv = ov * tanhf(cn);
      u16 hx, lx; bf_split(hv, hx, lx);
      const int par = ((t + 1) & 1) * (Bz * DH);
      hhi[par + b * DH + wg * 4 + j] = hx;
      hlo[par + b * DH + wg * 4 + j] = lx;
      hs[(b * Sz + t) * DH + wg * 4 + j] = hv;
    }
    grid_bar(arrive, rel, wg, tid, (unsigned)(t + 2));
  }
}

// ---- final FC: [16384,1024] @ [1024,512] + bias, fp32, 64x64 tile, 4x4 micro ----
__global__ __launch_bounds__(256)
void lstm_fc(const float* __restrict__ hs, const float* __restrict__ Wfc,
             const float* __restrict__ bfc, float* __restrict__ out)
{
  __shared__ __align__(16) float Ash[16][68];
  __shared__ __align__(16) float Bsh[16][68];
  const int tid = threadIdx.x;
  const int mt = (int)(blockIdx.x >> 3) * 64;
  const int nt = (int)(blockIdx.x & 7) * 64;
  const int ty = tid >> 4, tx = tid & 15;
  const int am = tid & 63, ak = (tid >> 6) * 4;
  const int bk = tid >> 4, bn = (tid & 15) * 4;
  float acc[4][4] = {};
  for (int k0 = 0; k0 < DH; k0 += 16) {
    const float4 av = *(const float4*)&hs[(mt + am) * DH + k0 + ak];
    const float4 bv = *(const float4*)&Wfc[(k0 + bk) * DOUT + nt + bn];
    Ash[ak + 0][am] = av.x;
    Ash[ak + 1][am] = av.y;
    Ash[ak + 2][am] = av.z;
    Ash[ak + 3][am] = av.w;
    *(float4*)&Bsh[bk][bn] = bv;
    __syncthreads();
    #pragma unroll
    for (int kk = 0; kk < 16; ++kk) {
      const float4 a = *(const float4*)&Ash[kk][ty * 4];
      const float4 b = *(const float4*)&Bsh[kk][tx * 4];
      const float avv[4] = {a.x, a.y, a.z, a.w};
      const float bvv[4] = {b.x, b.y, b.z, b.w};
      #pragma unroll
      for (int i = 0; i < 4; ++i)
        #pragma unroll
        for (int j = 0; j < 4; ++j)
          acc[i][j] = fmaf(avv[i], bvv[j], acc[i][j]);
    }
    __syncthreads();
  }
  const float4 bb = *(const float4*)&bfc[nt + tx * 4];
  const float bias[4] = {bb.x, bb.y, bb.z, bb.w};
  #pragma unroll
  for (int i = 0; i < 4; ++i) {
    float4 o;
    o.x = acc[i][0] + bias[0];
    o.y = acc[i][1] + bias[1];
    o.z = acc[i][2] + bias[2];
    o.w = acc[i][3] + bias[3];
    *(float4*)&out[(mt + ty * 4 + i) * DOUT + nt + tx * 4] = o;
  }
}

extern "C" void kernel_launch(void* const* d_in, const int* in_sizes, int n_in,
                              void* d_out, int out_size, void* d_ws, size_t ws_size,
                              hipStream_t stream) {
  const float* x   = (const float*)d_in[0];
  const float* Wf  = (const float*)d_in[1];
  const float* bf  = (const float*)d_in[2];
  const float* Wi  = (const float*)d_in[3];
  const float* bi  = (const float*)d_in[4];
  const float* Wg  = (const float*)d_in[5];
  const float* bg  = (const float*)d_in[6];
  const float* Wo  = (const float*)d_in[7];
  const float* bo  = (const float*)d_in[8];
  const float* Wfc = (const float*)d_in[9];
  const float* bfc = (const float*)d_in[10];
  float* out = (float*)d_out;

  // ws layout: [0,32K) arrive flags (128B-padded) | [32K] rel flag | 64K: data
  char* w = (char*)d_ws;
  unsigned* arrive = (unsigned*)w;
  unsigned* rel    = (unsigned*)(w + 32768);
  size_t off = 65536;
  u16* hhi = (u16*)(w + off);                         off += 2u * Bz * DH * sizeof(u16);
  u16* hlo = (u16*)(w + off);                         off += 2u * Bz * DH * sizeof(u16);
  u16* xhi = (u16*)(w + off);                         off += (size_t)Bz * Sz * DIN * sizeof(u16);
  u16* xlo = (u16*)(w + off);                         off += (size_t)Bz * Sz * DIN * sizeof(u16);
  float* hs = (float*)(w + off);

  hipMemsetAsync(d_ws, 0, 65536, stream);             // zero all barrier flags

  const int xN = Bz * Sz * DIN;                       // 8,388,608 (exactly 8192*256*4)
  hipLaunchKernelGGL(xsplit, dim3(xN / (256 * 4)), dim3(256), 0, stream, x, xhi, xlo);

  hipLaunchKernelGGL(lstm_rec, dim3(NWG), dim3(NTH), 0, stream,
                     xhi, xlo, Wf, bf, Wi, bi, Wg, bg, Wo, bo, hhi, hlo, hs,
                     arrive, rel);

  hipLaunchKernelGGL(lstm_fc, dim3((Bz * Sz / 64) * (DOUT / 64)), dim3(256), 0, stream,
                     hs, Wfc, bfc, out);
}